// Round 11
// baseline (372.926 us; speedup 1.0000x reference)
//
#include <hip/hip_runtime.h>
#include <hip/hip_fp16.h>

// LightGCN 3-layer propagation. out layout: [4, N_NODES, DIM] f32.
//   layer 0 = embeddings (copy); layer l = SpMM(layer l-1).
//
// Ledger:
//  R4-R8: scatter fight. dst-ranges(%8)+NT loads = 54.6 MB WRITE, 63us;
//      atomic rule: per-address returning-atomic multiplicity <= tens.
//  R8: hex (16-chain) spmm < oct (8) -> spmm throughput-bound.
//  R10: fp16 mirror spmm: 366us, absmax 0.25. BEST baseline.
//  R11: src-range-sorted CSR neutral (deg~12 consumed concurrently).
//      Gather reuse/XCD < 1 -> ~100 MB/layer random-line traffic is the
//      spmm floor (~50-65us/layer). 
//  R12: NT on spmm pairs/yh REGRESSED (+30us): yh is next layer's gather
//      source; pairs lines re-read 8x. NT only for never-reread data.
//  R13: scatter occupancy 37->62%, duration UNCHANGED -> not latency-bound;
//      fixed traffic wall (57 FETCH of 8x replicated reads + 54 WRITE amp).
//  R14 (this round): radix-partition build, zero replication:
//      hist_part: deg atomics + per-block dst-range counts (LDS) -> cntT.
//      scan cntT -> block-private regions. partA: single re-read, append to
//      8 private SEQUENTIAL streams (LDS positions, no global atomics) ->
//      lines fill block-locally = no write amp. partB: per range r (=XCD
//      via %8), sequential 1.2MB bucket read (NT) + cur-atomic scatter into
//      the contiguous 1.2MB pairs region -> L2 holds it, lines merge.

#define N_NODES 100000
#define DIM 64
#define SCAN_CHUNK 1024

#define NR 8                              // dst ranges
#define RSIZE ((N_NODES + NR - 1) / NR)   // 12500 nodes per range
#define NBLK 256                          // partition blocks (hist_part/partA)
#define PBR 32                            // partB blocks per range
#define SLICES 256                        // legacy fallback scatter

typedef int   vint4   __attribute__((ext_vector_type(4)));
typedef int   vint2   __attribute__((ext_vector_type(2)));
typedef float vfloat4 __attribute__((ext_vector_type(4)));

union HU { unsigned u; __half2 h; };

// ---------------- layer 0: copy f32 + build fp16 mirror ----------------
__global__ void convert_kernel(const float* __restrict__ emb, float* __restrict__ out0,
                               unsigned short* __restrict__ xh0, int n8) {
    int i = blockIdx.x * blockDim.x + threadIdx.x;   // 8 floats per thread
    if (i >= n8) return;
    const vfloat4* e4 = (const vfloat4*)emb;
    vfloat4 a = __builtin_nontemporal_load(e4 + 2 * i);
    vfloat4 b = __builtin_nontemporal_load(e4 + 2 * i + 1);
    vfloat4* o4 = (vfloat4*)out0;
    __builtin_nontemporal_store(a, o4 + 2 * i);
    __builtin_nontemporal_store(b, o4 + 2 * i + 1);
    HU c0, c1, c2, c3;
    c0.h = __float22half2_rn(make_float2(a[0], a[1]));
    c1.h = __float22half2_rn(make_float2(a[2], a[3]));
    c2.h = __float22half2_rn(make_float2(b[0], b[1]));
    c3.h = __float22half2_rn(make_float2(b[2], b[3]));
    vint4 p = { (int)c0.u, (int)c1.u, (int)c2.u, (int)c3.u };
    ((vint4*)xh0)[i] = p;
}

// ---------------- radix-partition CSR build ----------------

// Node-degree atomics + per-(block,range) counts. cntT[r*NBLK + b].
__global__ void hist_part_kernel(const int* __restrict__ edst, int* __restrict__ deg,
                                 int* __restrict__ cntT, int E, int chunk) {
    __shared__ int lcnt[NR];
    if (threadIdx.x < NR) lcnt[threadIdx.x] = 0;
    __syncthreads();
    const int b = blockIdx.x;
    const int e0 = b * chunk;
    const int e1 = min(e0 + chunk, E);
    if (e0 < E) {
        const int nv = (e1 - e0) >> 2;
        const vint4* d4 = (const vint4*)(edst + e0);
        for (int i = threadIdx.x; i < nv; i += blockDim.x) {
            vint4 d = __builtin_nontemporal_load(d4 + i);
            #pragma unroll
            for (int j = 0; j < 4; ++j) {
                atomicAdd(&deg[d[j]], 1);            // fire-and-forget
                atomicAdd(&lcnt[d[j] / RSIZE], 1);   // LDS
            }
        }
        for (int e = e0 + (nv << 2) + threadIdx.x; e < e1; e += blockDim.x) {
            int d = edst[e];
            atomicAdd(&deg[d], 1);
            atomicAdd(&lcnt[d / RSIZE], 1);
        }
    }
    __syncthreads();
    if (threadIdx.x < NR) cntT[threadIdx.x * NBLK + b] = lcnt[threadIdx.x];
}

// Per-block exclusive scan over chunks of 1024; emits per-block totals.
__global__ void scan1_kernel(const int* __restrict__ src, int* __restrict__ dst,
                             int* __restrict__ bsum, int n) {
    __shared__ int sdata[256];
    int tid = threadIdx.x;
    int base = blockIdx.x * SCAN_CHUNK + tid * 4;
    int v[4];
    #pragma unroll
    for (int i = 0; i < 4; ++i) v[i] = (base + i < n) ? src[base + i] : 0;
    int tsum = v[0] + v[1] + v[2] + v[3];
    sdata[tid] = tsum;
    __syncthreads();
    for (int d = 1; d < 256; d <<= 1) {
        int t = (tid >= d) ? sdata[tid - d] : 0;
        __syncthreads();
        sdata[tid] += t;
        __syncthreads();
    }
    int excl = sdata[tid] - tsum;
    if (tid == 255) bsum[blockIdx.x] = sdata[255];
    int run = excl;
    #pragma unroll
    for (int i = 0; i < 4; ++i) {
        if (base + i < n) dst[base + i] = run;
        run += v[i];
    }
}

// Single-block exclusive scan of up to 2048 values (1024 thr x 2), in-place.
__global__ void scan2b_kernel(int* __restrict__ a, int nb) {
    __shared__ int s[1024];
    int t = threadIdx.x;
    int i0 = 2 * t, i1 = 2 * t + 1;
    int v0 = (i0 < nb) ? a[i0] : 0;
    int v1 = (i1 < nb) ? a[i1] : 0;
    s[t] = v0 + v1;
    __syncthreads();
    for (int d = 1; d < 1024; d <<= 1) {
        int tt = (t >= d) ? s[t - d] : 0;
        __syncthreads();
        s[t] += tt;
        __syncthreads();
    }
    int excl = s[t] - (v0 + v1);
    if (i0 < nb) a[i0] = excl;
    if (i1 < nb) a[i1] = excl + v0;
}

// Adds block prefix; seeds cur = off.
__global__ void scan3_kernel(int* __restrict__ off, int* __restrict__ cur,
                             const int* __restrict__ bsum, int n) {
    int i = blockIdx.x * blockDim.x + threadIdx.x;
    if (i < n) {
        int v = off[i] + bsum[i / SCAN_CHUNK];
        off[i] = v;
        cur[i] = v;
    }
}

// partA: block b re-reads its slice once, appends each edge to its PRIVATE
// per-range stream (position from LDS counter seeded with scanned cntT).
// Pack: x = src | (dlocal<<17)  (src<2^17, dlocal<12500<2^14), y = weight.
__global__ void partA_kernel(const int* __restrict__ esrc, const int* __restrict__ edst,
                             const float* __restrict__ ew, const int* __restrict__ cntT,
                             int2* __restrict__ tmp, int E, int chunk) {
    __shared__ int lcur[NR];
    const int b = blockIdx.x;
    if (threadIdx.x < NR) lcur[threadIdx.x] = cntT[threadIdx.x * NBLK + b];
    __syncthreads();
    const int e0 = b * chunk;
    if (e0 >= E) return;
    const int e1 = min(e0 + chunk, E);
    const int nv = (e1 - e0) >> 2;
    const vint4*   s4 = (const vint4*)(esrc + e0);
    const vint4*   d4 = (const vint4*)(edst + e0);
    const vfloat4* w4 = (const vfloat4*)(ew + e0);
    for (int i = threadIdx.x; i < nv; i += blockDim.x) {
        vint4 dd = __builtin_nontemporal_load(d4 + i);
        vint4 ss = __builtin_nontemporal_load(s4 + i);
        vfloat4 ww = __builtin_nontemporal_load(w4 + i);
        #pragma unroll
        for (int j = 0; j < 4; ++j) {
            int d = dd[j];
            int r = d / RSIZE;
            int dl = d - r * RSIZE;
            int pos = atomicAdd(&lcur[r], 1);
            int2 pr;
            pr.x = ss[j] | (dl << 17);
            pr.y = __float_as_int(ww[j]);
            tmp[pos] = pr;
        }
    }
    for (int e = e0 + (nv << 2) + threadIdx.x; e < e1; e += blockDim.x) {
        int d = edst[e];
        int r = d / RSIZE;
        int dl = d - r * RSIZE;
        int pos = atomicAdd(&lcur[r], 1);
        int2 pr;
        pr.x = esrc[e] | (dl << 17);
        pr.y = __float_as_int(ew[e]);
        tmp[pos] = pr;
    }
}

// partB: range r (= blockIdx%8, XCD rr) reads its contiguous bucket (NT,
// read-once) and scatters into the contiguous pairs region for dst range r.
__global__ void partB_kernel(const int2* __restrict__ tmp, const int* __restrict__ cntT,
                             int* __restrict__ cur, int2* __restrict__ pairs, int E) {
    const int r  = blockIdx.x & (NR - 1);
    const int bi = blockIdx.x >> 3;            // 0..PBR-1
    const int s0 = cntT[r * NBLK];
    const int s1 = (r == NR - 1) ? E : cntT[(r + 1) * NBLK];
    const int n  = s1 - s0;
    const int chunk = (n + PBR - 1) / PBR;
    const int b0 = s0 + bi * chunk;
    const int b1 = min(b0 + chunk, s1);
    const int rbase = r * RSIZE;
    for (int i = b0 + threadIdx.x; i < b1; i += blockDim.x) {
        vint2 pr = __builtin_nontemporal_load((const vint2*)(tmp + i));
        int src = pr[0] & 0x1FFFF;
        int dst = rbase + (int)(((unsigned)pr[0]) >> 17);
        int p = atomicAdd(&cur[dst], 1);
        int2 o;
        o.x = src;
        o.y = pr[1];
        pairs[p] = o;
    }
}

// ---------------- SpMM fp16-gather: one wave per node, oct scheme ----------
// R10-exact: plain pairs load, plain yh store, NT y store only.

__global__ void spmm_h_kernel(const unsigned short* __restrict__ xh,
                              const int2* __restrict__ pairs,
                              const int* __restrict__ off,
                              const int* __restrict__ deg,
                              float* __restrict__ y,
                              unsigned short* __restrict__ yh) {
    int gtid = blockIdx.x * blockDim.x + threadIdx.x;
    int node = gtid >> 6;
    int lane = threadIdx.x & 63;
    int o  = lane >> 3;
    int ol = lane & 7;
    if (node >= N_NODES) return;
    int s0 = off[node];
    int n  = deg[node];
    float a0 = 0.f, a1 = 0.f, a2 = 0.f, a3 = 0.f;
    float a4 = 0.f, a5 = 0.f, a6 = 0.f, a7 = 0.f;   // dims [8ol, 8ol+8)
    for (int k = o; k < n; k += 8) {
        int2 pr = pairs[s0 + k];                     // uniform within oct
        float w = __int_as_float(pr.y);
        const vint4* row = (const vint4*)(xh + (size_t)pr.x * DIM);
        vint4 v = row[ol];                           // 8 lanes x 16 B = 128 B row
        HU c; float2 f;
        c.u = (unsigned)v[0]; f = __half22float2(c.h); a0 += w * f.x; a1 += w * f.y;
        c.u = (unsigned)v[1]; f = __half22float2(c.h); a2 += w * f.x; a3 += w * f.y;
        c.u = (unsigned)v[2]; f = __half22float2(c.h); a4 += w * f.x; a5 += w * f.y;
        c.u = (unsigned)v[3]; f = __half22float2(c.h); a6 += w * f.x; a7 += w * f.y;
    }
    #pragma unroll
    for (int d = 8; d <= 32; d <<= 1) {
        a0 += __shfl_xor(a0, d); a1 += __shfl_xor(a1, d);
        a2 += __shfl_xor(a2, d); a3 += __shfl_xor(a3, d);
        a4 += __shfl_xor(a4, d); a5 += __shfl_xor(a5, d);
        a6 += __shfl_xor(a6, d); a7 += __shfl_xor(a7, d);
    }
    if (o == 0) {
        float* yr = y + (size_t)node * DIM + ol * 8;
        vfloat4 r0 = { a0, a1, a2, a3 };
        vfloat4 r1 = { a4, a5, a6, a7 };
        __builtin_nontemporal_store(r0, (vfloat4*)yr);
        __builtin_nontemporal_store(r1, (vfloat4*)yr + 1);
        HU c0, c1, c2, c3;
        c0.h = __float22half2_rn(make_float2(a0, a1));
        c1.h = __float22half2_rn(make_float2(a2, a3));
        c2.h = __float22half2_rn(make_float2(a4, a5));
        c3.h = __float22half2_rn(make_float2(a6, a7));
        vint4 p = { (int)c0.u, (int)c1.u, (int)c2.u, (int)c3.u };
        *((vint4*)(yh + (size_t)node * DIM + ol * 8)) = p;
    }
}

// ---------------- fallback kernels (f32 mid path + atomic path) ----------

__global__ void hist_kernel(const int* __restrict__ edst, int* __restrict__ deg, int E) {
    int i = blockIdx.x * blockDim.x + threadIdx.x;
    int nv = E >> 2;
    if (i < nv) {
        vint4 d = __builtin_nontemporal_load(((const vint4*)edst) + i);
        atomicAdd(&deg[d[0]], 1);
        atomicAdd(&deg[d[1]], 1);
        atomicAdd(&deg[d[2]], 1);
        atomicAdd(&deg[d[3]], 1);
    }
    if (i == 0) {
        for (int e = nv << 2; e < E; ++e) atomicAdd(&deg[edst[e]], 1);
    }
}

__global__ void scatter_range_kernel(const int* __restrict__ esrc, const int* __restrict__ edst,
                                     const float* __restrict__ ew, int* __restrict__ cur,
                                     int2* __restrict__ pairs, int E, int chunk) {
    const int r = blockIdx.x & (NR - 1);
    const int s = blockIdx.x / NR;
    const int lo = r * RSIZE;
    const int hi = min(lo + RSIZE, N_NODES);
    const int e0 = s * chunk;
    if (e0 >= E) return;
    const int e1 = min(e0 + chunk, E);
    const int nv = (e1 - e0) >> 2;
    const vint4*   s4 = (const vint4*)(esrc + e0);
    const vint4*   d4 = (const vint4*)(edst + e0);
    const vfloat4* w4 = (const vfloat4*)(ew + e0);
    for (int i = threadIdx.x; i < nv; i += blockDim.x) {
        vint4 dd = __builtin_nontemporal_load(d4 + i);
        vint4 ss = __builtin_nontemporal_load(s4 + i);
        vfloat4 ww = __builtin_nontemporal_load(w4 + i);
        #pragma unroll
        for (int j = 0; j < 4; ++j) {
            int dj = dd[j];
            if (dj >= lo && dj < hi) {
                int p = atomicAdd(&cur[dj], 1);
                int2 pr;
                pr.x = ss[j];
                pr.y = __float_as_int(ww[j]);
                pairs[p] = pr;
            }
        }
    }
    for (int e = e0 + (nv << 2) + threadIdx.x; e < e1; e += blockDim.x) {
        int dj = edst[e];
        if (dj >= lo && dj < hi) {
            int p = atomicAdd(&cur[dj], 1);
            int2 pr;
            pr.x = esrc[e];
            pr.y = __float_as_int(ew[e]);
            pairs[p] = pr;
        }
    }
}

__global__ void spmm_csr_kernel(const float* __restrict__ x,
                                const int2* __restrict__ pairs,
                                const int* __restrict__ off,
                                const int* __restrict__ deg,
                                float* __restrict__ y) {
    int gtid = blockIdx.x * blockDim.x + threadIdx.x;
    int node = gtid >> 6;
    int lane = threadIdx.x & 63;
    int o  = lane >> 3;
    int ol = lane & 7;
    if (node >= N_NODES) return;
    int s0 = off[node];
    int n  = deg[node];
    float4 a0 = make_float4(0.f, 0.f, 0.f, 0.f);
    float4 a1 = a0;
    for (int k = o; k < n; k += 8) {
        int2 pr = pairs[s0 + k];
        float w = __int_as_float(pr.y);
        const float4* row = (const float4*)(x + (size_t)pr.x * DIM);
        float4 v0 = row[ol];
        float4 v1 = row[ol + 8];
        a0.x += w * v0.x; a0.y += w * v0.y; a0.z += w * v0.z; a0.w += w * v0.w;
        a1.x += w * v1.x; a1.y += w * v1.y; a1.z += w * v1.z; a1.w += w * v1.w;
    }
    #pragma unroll
    for (int d = 8; d <= 32; d <<= 1) {
        a0.x += __shfl_xor(a0.x, d); a0.y += __shfl_xor(a0.y, d);
        a0.z += __shfl_xor(a0.z, d); a0.w += __shfl_xor(a0.w, d);
        a1.x += __shfl_xor(a1.x, d); a1.y += __shfl_xor(a1.y, d);
        a1.z += __shfl_xor(a1.z, d); a1.w += __shfl_xor(a1.w, d);
    }
    if (o == 0) {
        vfloat4* yrow = (vfloat4*)(y + (size_t)node * DIM);
        vfloat4 r0 = { a0.x, a0.y, a0.z, a0.w };
        vfloat4 r1 = { a1.x, a1.y, a1.z, a1.w };
        __builtin_nontemporal_store(r0, yrow + ol);
        __builtin_nontemporal_store(r1, yrow + ol + 8);
    }
}

__global__ void spmm_atomic_kernel(const float* __restrict__ x, const float* __restrict__ ew,
                                   const int* __restrict__ esrc, const int* __restrict__ edst,
                                   float* __restrict__ y, int n_edges) {
    long long tid = (long long)blockIdx.x * blockDim.x + threadIdx.x;
    int e = (int)(tid >> 6);
    int d = (int)(tid & 63);
    if (e >= n_edges) return;
    int s = esrc[e]; int t = edst[e]; float w = ew[e];
    atomicAdd(&y[(long long)t * DIM + d], w * x[(long long)s * DIM + d]);
}

extern "C" void kernel_launch(void* const* d_in, const int* in_sizes, int n_in,
                              void* d_out, int out_size, void* d_ws, size_t ws_size,
                              hipStream_t stream) {
    const float* emb  = (const float*)d_in[0];
    const float* ew   = (const float*)d_in[1];
    const int*   esrc = (const int*)d_in[2];
    const int*   edst = (const int*)d_in[3];
    float* out = (float*)d_out;

    const int E = in_sizes[1];
    const size_t layer_elems = (size_t)N_NODES * DIM;

    const size_t need_new = (size_t)E * 16 + 2 * layer_elems * 2
                          + (size_t)3 * N_NODES * 4 + (size_t)(NBLK * NR + 1024) * 4 + 1024;
    const size_t need_f32 = (size_t)E * 8 + (size_t)3 * N_NODES * 4 + 1024;

    // N_NODES must split exactly into NR ranges for the packing (it does:
    // 100000 = 8 * 12500); src < 2^17 and dlocal < 2^14 hold by construction.

    if (ws_size >= need_new && E >= 4) {
        char* w = (char*)d_ws;
        int2* pairs = (int2*)w;
        int2* tmp   = (int2*)(w + (size_t)E * 8);
        unsigned short* xh0 = (unsigned short*)(w + (size_t)E * 16);
        unsigned short* xh1 = xh0 + layer_elems;
        int* deg  = (int*)(xh1 + layer_elems);
        int* cur  = deg + N_NODES;
        int* off  = cur + N_NODES;
        int* cntT = off + N_NODES;          // NBLK*NR = 2048 ints
        int* bsum = cntT + NBLK * NR;       // 128 ints

        hipMemsetAsync(deg, 0, (size_t)N_NODES * 4, stream);

        const int n8 = (int)(layer_elems / 8);
        convert_kernel<<<(n8 + 255) / 256, 256, 0, stream>>>(emb, out, xh0, n8);

        const int pchunk = (((E + NBLK - 1) / NBLK) + 3) & ~3;
        hist_part_kernel<<<NBLK, 256, 0, stream>>>(edst, deg, cntT, E, pchunk);

        const int nscan = (N_NODES + SCAN_CHUNK - 1) / SCAN_CHUNK;   // 98
        scan1_kernel<<<nscan, 256, 0, stream>>>(deg, off, bsum, N_NODES);
        scan2b_kernel<<<1, 1024, 0, stream>>>(bsum, nscan);
        scan3_kernel<<<(N_NODES + 255) / 256, 256, 0, stream>>>(off, cur, bsum, N_NODES);

        scan2b_kernel<<<1, 1024, 0, stream>>>(cntT, NBLK * NR);      // 2048

        partA_kernel<<<NBLK, 256, 0, stream>>>(esrc, edst, ew, cntT, tmp, E, pchunk);
        partB_kernel<<<NR * PBR, 256, 0, stream>>>(tmp, cntT, cur, pairs, E);

        const int nb = (N_NODES + 3) / 4;   // 4 waves (nodes) per 256-thread block
        unsigned short* xs[2] = { xh0, xh1 };
        for (int l = 1; l <= 3; ++l) {
            spmm_h_kernel<<<nb, 256, 0, stream>>>(
                xs[(l - 1) & 1], pairs, off, deg,
                out + (size_t)l * layer_elems, xs[l & 1]);
        }
    } else if (ws_size >= need_f32 && E >= 4) {
        char* w = (char*)d_ws;
        int2* pairs = (int2*)w;
        int* deg  = (int*)(w + (size_t)E * 8);
        int* cur  = deg + N_NODES;
        int* off  = cur + N_NODES;
        int* bsum = off + N_NODES;

        hipMemcpyAsync(out, emb, layer_elems * sizeof(float), hipMemcpyDeviceToDevice, stream);
        hipMemsetAsync(deg, 0, (size_t)N_NODES * 4, stream);
        const int nv4 = E >> 2;
        hist_kernel<<<(nv4 + 255) / 256, 256, 0, stream>>>(edst, deg, E);
        const int nscan = (N_NODES + SCAN_CHUNK - 1) / SCAN_CHUNK;
        scan1_kernel<<<nscan, 256, 0, stream>>>(deg, off, bsum, N_NODES);
        scan2b_kernel<<<1, 1024, 0, stream>>>(bsum, nscan);
        scan3_kernel<<<(N_NODES + 255) / 256, 256, 0, stream>>>(off, cur, bsum, N_NODES);
        const int chunk = (((E + SLICES - 1) / SLICES) + 3) & ~3;
        scatter_range_kernel<<<NR * SLICES, 256, 0, stream>>>(esrc, edst, ew, cur, pairs, E, chunk);
        const int nb = (N_NODES + 3) / 4;
        for (int l = 1; l <= 3; ++l) {
            spmm_csr_kernel<<<nb, 256, 0, stream>>>(
                out + (size_t)(l - 1) * layer_elems, pairs, off, deg,
                out + (size_t)l * layer_elems);
        }
    } else {
        hipMemcpyAsync(out, emb, layer_elems * sizeof(float), hipMemcpyDeviceToDevice, stream);
        hipMemsetAsync(out + layer_elems, 0, 3 * layer_elems * sizeof(float), stream);
        const long long total_threads = (long long)E * 64;
        const int blocks = (int)((total_threads + 255) / 256);
        for (int l = 1; l <= 3; ++l) {
            spmm_atomic_kernel<<<blocks, 256, 0, stream>>>(
                out + (size_t)(l - 1) * layer_elems, ew, esrc, edst,
                out + (size_t)l * layer_elems, E);
        }
    }
}

// Round 12
// 365.684 us; speedup vs baseline: 1.0198x; 1.0198x over previous
//
#include <hip/hip_runtime.h>
#include <hip/hip_fp16.h>

// LightGCN 3-layer propagation. out layout: [4, N_NODES, DIM] f32.
//   layer 0 = embeddings (copy); layer l = SpMM(layer l-1).
//
// FINAL FORM (R15 = R10 exact, the best-measured config: 366.3 us).
//
// Ledger (what was tried and what it taught):
//  R5:  bucket-stream scatter: 755us. >700 returning atomics/addr serialize
//       at the coherence point (~410ns each). Multiplicity must stay <= tens.
//  R6:  dst-ranges(blockIdx%8)+NT edge loads: WRITE 77->54.6 MB, 63us. BEST
//       build. Residual 5x write-amp on random 8B stores is structural.
//  R7:  physical-XCD binding (s_getreg XCC_ID): WRITE unchanged -> locality
//       of the issuing XCD is NOT the write-amp mechanism.
//  R8:  no-range scatter: WRITE 77.8, 100us -> ranges+NT are necessary.
//       hex spmm (16 chains) < oct (8) -> gather-throughput-bound.
//  R10: fp16 mirror spmm (128B rows, f32 accum, exact f32 out): 366us,
//       absmax 0.25. Byte-halving saved only ~9us/layer -> line-bound.
//  R11: src-range-sorted CSR: neutral. deg~12 is consumed concurrently, so
//       segment order cannot localize; per-XCD gather reuse < 1 ->
//       ~100 MB/layer random-line traffic is irreducible.
//  R12: NT pairs-load/yh-store: REGRESSED +30us. yh is the next layer's
//       gather source; pairs lines re-read 8x. NT only for never-reread.
//  R13: scatter occupancy 37->62%: duration unchanged -> traffic wall,
//       not latency. R14: radix-partition build (zero replication, block-
//       private sequential streams): neutral -> all build structures hit
//       the same ~63us random-8B-granule wall.
//
// Composed floor: fill/restore ~78 (harness) + convert 12 + hist/scans 11 +
// scatter 63 (wall) + 3 x spmm ~61 (random-line floor) ~= 360us. This config
// measures 366 -> within a few % of the floor.

#define N_NODES 100000
#define DIM 64
#define SCAN_CHUNK 1024

#define NR 8                              // dst ranges (XCD round-robin)
#define RSIZE ((N_NODES + NR - 1) / NR)   // 12500 nodes per range
#define SLICES 128                        // edge slices per range

typedef int   vint4   __attribute__((ext_vector_type(4)));
typedef float vfloat4 __attribute__((ext_vector_type(4)));

union HU { unsigned u; __half2 h; };

// ---------------- layer 0: copy f32 + build fp16 mirror ----------------
__global__ void convert_kernel(const float* __restrict__ emb, float* __restrict__ out0,
                               unsigned short* __restrict__ xh0, int n8) {
    int i = blockIdx.x * blockDim.x + threadIdx.x;   // 8 floats per thread
    if (i >= n8) return;
    const vfloat4* e4 = (const vfloat4*)emb;
    vfloat4 a = __builtin_nontemporal_load(e4 + 2 * i);
    vfloat4 b = __builtin_nontemporal_load(e4 + 2 * i + 1);
    vfloat4* o4 = (vfloat4*)out0;
    __builtin_nontemporal_store(a, o4 + 2 * i);
    __builtin_nontemporal_store(b, o4 + 2 * i + 1);
    HU c0, c1, c2, c3;
    c0.h = __float22half2_rn(make_float2(a[0], a[1]));
    c1.h = __float22half2_rn(make_float2(a[2], a[3]));
    c2.h = __float22half2_rn(make_float2(b[0], b[1]));
    c3.h = __float22half2_rn(make_float2(b[2], b[3]));
    vint4 p = { (int)c0.u, (int)c1.u, (int)c2.u, (int)c3.u };
    ((vint4*)xh0)[i] = p;
}

// ---------------- CSR build (R10-proven) ----------------

__global__ void hist_kernel(const int* __restrict__ edst, int* __restrict__ deg, int E) {
    int i = blockIdx.x * blockDim.x + threadIdx.x;
    int nv = E >> 2;
    if (i < nv) {
        vint4 d = __builtin_nontemporal_load(((const vint4*)edst) + i);
        atomicAdd(&deg[d[0]], 1);
        atomicAdd(&deg[d[1]], 1);
        atomicAdd(&deg[d[2]], 1);
        atomicAdd(&deg[d[3]], 1);
    }
    if (i == 0) {
        for (int e = nv << 2; e < E; ++e) atomicAdd(&deg[edst[e]], 1);
    }
}

__global__ void scan1_kernel(const int* __restrict__ src, int* __restrict__ dst,
                             int* __restrict__ bsum, int n) {
    __shared__ int sdata[256];
    int tid = threadIdx.x;
    int base = blockIdx.x * SCAN_CHUNK + tid * 4;
    int v[4];
    #pragma unroll
    for (int i = 0; i < 4; ++i) v[i] = (base + i < n) ? src[base + i] : 0;
    int tsum = v[0] + v[1] + v[2] + v[3];
    sdata[tid] = tsum;
    __syncthreads();
    for (int d = 1; d < 256; d <<= 1) {
        int t = (tid >= d) ? sdata[tid - d] : 0;
        __syncthreads();
        sdata[tid] += t;
        __syncthreads();
    }
    int excl = sdata[tid] - tsum;
    if (tid == 255) bsum[blockIdx.x] = sdata[255];
    int run = excl;
    #pragma unroll
    for (int i = 0; i < 4; ++i) {
        if (base + i < n) dst[base + i] = run;
        run += v[i];
    }
}

__global__ void scan2_kernel(int* __restrict__ bsum, int nb) {
    __shared__ int s[128];
    int tid = threadIdx.x;
    int v = (tid < nb) ? bsum[tid] : 0;
    s[tid] = v;
    __syncthreads();
    for (int d = 1; d < 128; d <<= 1) {
        int t = (tid >= d) ? s[tid - d] : 0;
        __syncthreads();
        s[tid] += t;
        __syncthreads();
    }
    if (tid < nb) bsum[tid] = s[tid] - v;   // exclusive
}

// Adds block prefix; seeds cur = off so scatter needs no off gather.
__global__ void scan3_kernel(int* __restrict__ off, int* __restrict__ cur,
                             const int* __restrict__ bsum, int n) {
    int i = blockIdx.x * blockDim.x + threadIdx.x;
    if (i < n) {
        int v = off[i] + bsum[i / SCAN_CHUNK];
        off[i] = v;
        cur[i] = v;
    }
}

// R6-proven scatter: dst-range partitioned (blockIdx%8) + NT edge streams.
__global__ void scatter_range_kernel(const int* __restrict__ esrc, const int* __restrict__ edst,
                                     const float* __restrict__ ew, int* __restrict__ cur,
                                     int2* __restrict__ pairs, int E, int chunk) {
    const int r = blockIdx.x & (NR - 1);
    const int s = blockIdx.x / NR;
    const int lo = r * RSIZE;
    const int hi = min(lo + RSIZE, N_NODES);
    const int e0 = s * chunk;
    if (e0 >= E) return;
    const int e1 = min(e0 + chunk, E);
    const int nv = (e1 - e0) >> 2;
    const vint4*   s4 = (const vint4*)(esrc + e0);
    const vint4*   d4 = (const vint4*)(edst + e0);
    const vfloat4* w4 = (const vfloat4*)(ew + e0);
    for (int i = threadIdx.x; i < nv; i += blockDim.x) {
        vint4 dd = __builtin_nontemporal_load(d4 + i);
        vint4 ss = __builtin_nontemporal_load(s4 + i);
        vfloat4 ww = __builtin_nontemporal_load(w4 + i);
        #pragma unroll
        for (int j = 0; j < 4; ++j) {
            int dj = dd[j];
            if (dj >= lo && dj < hi) {
                int p = atomicAdd(&cur[dj], 1);
                int2 pr;
                pr.x = ss[j];
                pr.y = __float_as_int(ww[j]);
                pairs[p] = pr;
            }
        }
    }
    for (int e = e0 + (nv << 2) + threadIdx.x; e < e1; e += blockDim.x) {
        int dj = edst[e];
        if (dj >= lo && dj < hi) {
            int p = atomicAdd(&cur[dj], 1);
            int2 pr;
            pr.x = esrc[e];
            pr.y = __float_as_int(ew[e]);
            pairs[p] = pr;
        }
    }
}

// ---------------- SpMM fp16-gather: one wave per node, oct scheme ----------
// Oct o (lanes 8o..8o+7) handles edges k = o, o+8, ... Lane ol loads ONE
// vint4 = 16 B = 8 halves -> 8 lanes cover the full 128 B fp16 row.
// Plain pairs load (L1/L2-served, 8x line reuse), plain yh store (next
// layer's gather source must stay cacheable), NT y store only (never reread).

__global__ void spmm_h_kernel(const unsigned short* __restrict__ xh,
                              const int2* __restrict__ pairs,
                              const int* __restrict__ off,
                              const int* __restrict__ deg,
                              float* __restrict__ y,
                              unsigned short* __restrict__ yh) {
    int gtid = blockIdx.x * blockDim.x + threadIdx.x;
    int node = gtid >> 6;
    int lane = threadIdx.x & 63;
    int o  = lane >> 3;
    int ol = lane & 7;
    if (node >= N_NODES) return;
    int s0 = off[node];
    int n  = deg[node];
    float a0 = 0.f, a1 = 0.f, a2 = 0.f, a3 = 0.f;
    float a4 = 0.f, a5 = 0.f, a6 = 0.f, a7 = 0.f;   // dims [8ol, 8ol+8)
    for (int k = o; k < n; k += 8) {
        int2 pr = pairs[s0 + k];                     // uniform within oct
        float w = __int_as_float(pr.y);
        const vint4* row = (const vint4*)(xh + (size_t)pr.x * DIM);
        vint4 v = row[ol];                           // 8 lanes x 16 B = 128 B row
        HU c; float2 f;
        c.u = (unsigned)v[0]; f = __half22float2(c.h); a0 += w * f.x; a1 += w * f.y;
        c.u = (unsigned)v[1]; f = __half22float2(c.h); a2 += w * f.x; a3 += w * f.y;
        c.u = (unsigned)v[2]; f = __half22float2(c.h); a4 += w * f.x; a5 += w * f.y;
        c.u = (unsigned)v[3]; f = __half22float2(c.h); a6 += w * f.x; a7 += w * f.y;
    }
    #pragma unroll
    for (int d = 8; d <= 32; d <<= 1) {
        a0 += __shfl_xor(a0, d); a1 += __shfl_xor(a1, d);
        a2 += __shfl_xor(a2, d); a3 += __shfl_xor(a3, d);
        a4 += __shfl_xor(a4, d); a5 += __shfl_xor(a5, d);
        a6 += __shfl_xor(a6, d); a7 += __shfl_xor(a7, d);
    }
    if (o == 0) {
        float* yr = y + (size_t)node * DIM + ol * 8;
        vfloat4 r0 = { a0, a1, a2, a3 };
        vfloat4 r1 = { a4, a5, a6, a7 };
        __builtin_nontemporal_store(r0, (vfloat4*)yr);
        __builtin_nontemporal_store(r1, (vfloat4*)yr + 1);
        HU c0, c1, c2, c3;
        c0.h = __float22half2_rn(make_float2(a0, a1));
        c1.h = __float22half2_rn(make_float2(a2, a3));
        c2.h = __float22half2_rn(make_float2(a4, a5));
        c3.h = __float22half2_rn(make_float2(a6, a7));
        vint4 p = { (int)c0.u, (int)c1.u, (int)c2.u, (int)c3.u };
        *((vint4*)(yh + (size_t)node * DIM + ol * 8)) = p;
    }
}

// ---------------- f32 oct spmm (mid fallback) ----------------

__global__ void spmm_csr_kernel(const float* __restrict__ x,
                                const int2* __restrict__ pairs,
                                const int* __restrict__ off,
                                const int* __restrict__ deg,
                                float* __restrict__ y) {
    int gtid = blockIdx.x * blockDim.x + threadIdx.x;
    int node = gtid >> 6;
    int lane = threadIdx.x & 63;
    int o  = lane >> 3;
    int ol = lane & 7;
    if (node >= N_NODES) return;
    int s0 = off[node];
    int n  = deg[node];
    float4 a0 = make_float4(0.f, 0.f, 0.f, 0.f);
    float4 a1 = a0;
    for (int k = o; k < n; k += 8) {
        int2 pr = pairs[s0 + k];
        float w = __int_as_float(pr.y);
        const float4* row = (const float4*)(x + (size_t)pr.x * DIM);
        float4 v0 = row[ol];
        float4 v1 = row[ol + 8];
        a0.x += w * v0.x; a0.y += w * v0.y; a0.z += w * v0.z; a0.w += w * v0.w;
        a1.x += w * v1.x; a1.y += w * v1.y; a1.z += w * v1.z; a1.w += w * v1.w;
    }
    #pragma unroll
    for (int d = 8; d <= 32; d <<= 1) {
        a0.x += __shfl_xor(a0.x, d); a0.y += __shfl_xor(a0.y, d);
        a0.z += __shfl_xor(a0.z, d); a0.w += __shfl_xor(a0.w, d);
        a1.x += __shfl_xor(a1.x, d); a1.y += __shfl_xor(a1.y, d);
        a1.z += __shfl_xor(a1.z, d); a1.w += __shfl_xor(a1.w, d);
    }
    if (o == 0) {
        vfloat4* yrow = (vfloat4*)(y + (size_t)node * DIM);
        vfloat4 r0 = { a0.x, a0.y, a0.z, a0.w };
        vfloat4 r1 = { a1.x, a1.y, a1.z, a1.w };
        __builtin_nontemporal_store(r0, yrow + ol);
        __builtin_nontemporal_store(r1, yrow + ol + 8);
    }
}

// ---------------- atomic fallback ----------------

__global__ void spmm_atomic_kernel(const float* __restrict__ x, const float* __restrict__ ew,
                                   const int* __restrict__ esrc, const int* __restrict__ edst,
                                   float* __restrict__ y, int n_edges) {
    long long tid = (long long)blockIdx.x * blockDim.x + threadIdx.x;
    int e = (int)(tid >> 6);
    int d = (int)(tid & 63);
    if (e >= n_edges) return;
    int s = esrc[e]; int t = edst[e]; float w = ew[e];
    atomicAdd(&y[(long long)t * DIM + d], w * x[(long long)s * DIM + d]);
}

extern "C" void kernel_launch(void* const* d_in, const int* in_sizes, int n_in,
                              void* d_out, int out_size, void* d_ws, size_t ws_size,
                              hipStream_t stream) {
    const float* emb  = (const float*)d_in[0];
    const float* ew   = (const float*)d_in[1];
    const int*   esrc = (const int*)d_in[2];
    const int*   edst = (const int*)d_in[3];
    float* out = (float*)d_out;

    const int E = in_sizes[1];
    const size_t layer_elems = (size_t)N_NODES * DIM;

    const size_t need_h   = (size_t)E * 8 + 2 * layer_elems * 2 + (size_t)3 * N_NODES * 4 + 1024;
    const size_t need_f32 = (size_t)E * 8 + (size_t)3 * N_NODES * 4 + 1024;

    if (ws_size >= need_h && E >= 4) {
        char* w = (char*)d_ws;
        int2* pairs = (int2*)w;
        unsigned short* xh0 = (unsigned short*)(w + (size_t)E * 8);
        unsigned short* xh1 = xh0 + layer_elems;
        int* deg  = (int*)(xh1 + layer_elems);
        int* cur  = deg + N_NODES;
        int* off  = cur + N_NODES;
        int* bsum = off + N_NODES;     // 128 ints

        hipMemsetAsync(deg, 0, (size_t)N_NODES * 4, stream);

        const int n8 = (int)(layer_elems / 8);
        convert_kernel<<<(n8 + 255) / 256, 256, 0, stream>>>(emb, out, xh0, n8);

        const int nv4 = E >> 2;
        hist_kernel<<<(nv4 + 255) / 256, 256, 0, stream>>>(edst, deg, E);

        const int nscan = (N_NODES + SCAN_CHUNK - 1) / SCAN_CHUNK;   // 98
        scan1_kernel<<<nscan, 256, 0, stream>>>(deg, off, bsum, N_NODES);
        scan2_kernel<<<1, 128, 0, stream>>>(bsum, nscan);
        scan3_kernel<<<(N_NODES + 255) / 256, 256, 0, stream>>>(off, cur, bsum, N_NODES);

        const int chunk = (((E + SLICES - 1) / SLICES) + 3) & ~3;
        scatter_range_kernel<<<NR * SLICES, 256, 0, stream>>>(esrc, edst, ew, cur, pairs, E, chunk);

        const int nb = (N_NODES + 3) / 4;   // 4 waves (nodes) per 256-thread block
        unsigned short* xs[2] = { xh0, xh1 };
        for (int l = 1; l <= 3; ++l) {
            spmm_h_kernel<<<nb, 256, 0, stream>>>(
                xs[(l - 1) & 1], pairs, off, deg,
                out + (size_t)l * layer_elems, xs[l & 1]);
        }
    } else if (ws_size >= need_f32 && E >= 4) {
        char* w = (char*)d_ws;
        int2* pairs = (int2*)w;
        int* deg  = (int*)(w + (size_t)E * 8);
        int* cur  = deg + N_NODES;
        int* off  = cur + N_NODES;
        int* bsum = off + N_NODES;

        hipMemcpyAsync(out, emb, layer_elems * sizeof(float), hipMemcpyDeviceToDevice, stream);
        hipMemsetAsync(deg, 0, (size_t)N_NODES * 4, stream);
        const int nv4 = E >> 2;
        hist_kernel<<<(nv4 + 255) / 256, 256, 0, stream>>>(edst, deg, E);
        const int nscan = (N_NODES + SCAN_CHUNK - 1) / SCAN_CHUNK;
        scan1_kernel<<<nscan, 256, 0, stream>>>(deg, off, bsum, N_NODES);
        scan2_kernel<<<1, 128, 0, stream>>>(bsum, nscan);
        scan3_kernel<<<(N_NODES + 255) / 256, 256, 0, stream>>>(off, cur, bsum, N_NODES);
        const int chunk = (((E + SLICES - 1) / SLICES) + 3) & ~3;
        scatter_range_kernel<<<NR * SLICES, 256, 0, stream>>>(esrc, edst, ew, cur, pairs, E, chunk);
        const int nb = (N_NODES + 3) / 4;
        for (int l = 1; l <= 3; ++l) {
            spmm_csr_kernel<<<nb, 256, 0, stream>>>(
                out + (size_t)(l - 1) * layer_elems, pairs, off, deg,
                out + (size_t)l * layer_elems);
        }
    } else {
        hipMemcpyAsync(out, emb, layer_elems * sizeof(float), hipMemcpyDeviceToDevice, stream);
        hipMemsetAsync(out + layer_elems, 0, 3 * layer_elems * sizeof(float), stream);
        const long long total_threads = (long long)E * 64;
        const int blocks = (int)((total_threads + 255) / 256);
        for (int l = 1; l <= 3; ++l) {
            spmm_atomic_kernel<<<blocks, 256, 0, stream>>>(
                out + (size_t)(l - 1) * layer_elems, ew, esrc, edst,
                out + (size_t)l * layer_elems, E);
        }
    }
}